// Round 8
// baseline (589.873 us; speedup 1.0000x reference)
//
#include <hip/hip_runtime.h>
#include <hip/hip_bf16.h>

#define NVERT 40962
#define NFACE 81920
#define GRID_V ((NVERT + 3) / 4)      // 10241 blocks, 4 vertices/block (1/wave)

typedef unsigned int uint;
typedef __attribute__((ext_vector_type(4))) uint  uintx4;
typedef __attribute__((ext_vector_type(4))) float floatx4;
typedef __attribute__((ext_vector_type(8))) short shortx8;

// ---------- bf16 helpers (RNE) ----------
__device__ __forceinline__ uint packbf2(float a, float b) {
  uint ua = __float_as_uint(a); ua = ua + 0x7fffu + ((ua >> 16) & 1u);
  uint ub = __float_as_uint(b); ub = ub + 0x7fffu + ((ub >> 16) & 1u);
  return (ua >> 16) | (ub & 0xffff0000u);
}
__device__ __forceinline__ float2 unpackbf2(uint u) {
  float2 r;
  r.x = __uint_as_float(u << 16);
  r.y = __uint_as_float(u & 0xffff0000u);
  return r;
}
__device__ __forceinline__ short bfr(float x) {
  uint u = __float_as_uint(x);
  u = u + 0x7fffu + ((u >> 16) & 1u);
  return (short)(u >> 16);
}

// bijective XCD swizzle (m204)
__device__ __forceinline__ int swz(int blk, int nwg) {
  int q = nwg >> 3, r = nwg & 7;
  int xcd = blk & 7, idx = blk >> 3;
  return (xcd < r ? xcd * (q + 1) : r * (q + 1) + (xcd - r) * q) + idx;
}

// ---------- K0: transpose x[512,NV] f32 -> xT[NV,256] u32 (bf16x2), permuted --
__global__ __launch_bounds__(256) void k_transpose(const float* __restrict__ x,
                                                   uint* __restrict__ xT) {
  __shared__ float tile[32][33];
  int n0 = blockIdx.x * 32;
  int r0 = blockIdx.y * 32;
  int tx = threadIdx.x & 31;
  int ty = threadIdx.x >> 5;
#pragma unroll
  for (int i = 0; i < 32; i += 8) {
    int n = n0 + tx;
    tile[ty + i][tx] = (n < NVERT)
        ? __builtin_nontemporal_load(&x[(size_t)(r0 + ty + i) * NVERT + n]) : 0.f;
  }
  __syncthreads();
#pragma unroll
  for (int i = 0; i < 32; i += 16) {
    int nl = (threadIdx.x >> 4) + i;
    int u  = threadIdx.x & 15;
    int n  = n0 + nl;
    int ug = 16 * blockIdx.y + u;                       // global word index
    int up = (ug & 3) * 64 + (ug >> 4) * 4 + ((ug >> 2) & 3);
    if (n < NVERT)
      xT[(size_t)n * 256 + up] = packbf2(tile[2 * u][nl], tile[2 * u + 1][nl]);
  }
}

// ---------- K0b: pre-convert coeffs -> bf16 MFMA B-fragments ----------
__global__ __launch_bounds__(256) void k_prepw(const float* __restrict__ coeffs,
                                               short* __restrict__ wsW) {
  int t = threadIdx.x;
  int ks = t >> 6, lane = t & 63;
  int bm = lane & 15, h = lane >> 4;
  const float* wp0 = coeffs + (size_t)bm * 128 + 32 * ks + 8 * h;
  shortx8 f0, f1;
#pragma unroll
  for (int j = 0; j < 8; ++j) {
    f0[j] = bfr(wp0[j]);
    f1[j] = bfr(wp0[16 * 128 + j]);
  }
  *(shortx8*)(wsW + ((size_t)(ks * 2 + 0) * 64 + lane) * 8) = f0;
  *(shortx8*)(wsW + ((size_t)(ks * 2 + 1) * 64 + lane) * 8) = f1;
}

// ---------- K0c: composite operator tables: F2V∘diag(EW/NS)∘G --------------
// per vertex n: 54 entries (6 faces x 3 comps x 3 cols):
//   cols[n*64+j*9+comp*3+k] = Gc[3*(comp*NF+f_j)+k]
//   wew [same]              = Fv(n,j)*EW[f_j,comp]*Gv[...]
//   wns [same]              = Fv(n,j)*NS[f_j,comp]*Gv[...]
__global__ __launch_bounds__(256) void k_prep(
    const int* __restrict__ Fc, const float* __restrict__ Fv,
    const int* __restrict__ Gc, const float* __restrict__ Gv,
    const float* __restrict__ EW, const float* __restrict__ NS,
    int* __restrict__ cols, float* __restrict__ wew, float* __restrict__ wns) {
  int idx = blockIdx.x * 256 + threadIdx.x;     // idx = 6*n + j
  if (idx >= NVERT * 6) return;
  int n = idx / 6, j = idx - 6 * n;
  int f = Fc[idx];
  float wv = Fv[idx];
  int bo = n * 64 + j * 9;
#pragma unroll
  for (int comp = 0; comp < 3; ++comp) {
    float e = wv * EW[3 * f + comp];
    float s = wv * NS[3 * f + comp];
    int gb = 3 * (comp * NFACE + f);
#pragma unroll
    for (int k = 0; k < 3; ++k) {
      int   c  = Gc[gb + k];
      float gv = Gv[gb + k];
      cols[bo + comp * 3 + k] = c;
      wew[bo + comp * 3 + k]  = e * gv;
      wns[bo + comp * 3 + k]  = s * gv;
    }
  }
}

// ---------- K2: fully fused per-vertex kernel (no gf intermediate) ----------
__global__ __launch_bounds__(256) void k_vfused(
    const uint* __restrict__ xT,
    const int* __restrict__ Lc, const float* __restrict__ Lv,
    const int* __restrict__ cols, const float* __restrict__ wew,
    const float* __restrict__ wns,
    const short* __restrict__ wsW, const float* __restrict__ bias,
    float* __restrict__ out) {
  const int t = threadIdx.x, lane = t & 63;
  const int n = __builtin_amdgcn_readfirstlane(swz(blockIdx.x, GRID_V) * 4 + (t >> 6));
  if (n >= NVERT) return;
  const int h = lane >> 4, bm = lane & 15;
  const int voff = 4 * lane;

  // identity row
  uintx4 idw = *(const uintx4*)(xT + (size_t)n * 256 + voff);

  // Laplacian: 7 direct gathers
  float lap[4][2];
#pragma unroll
  for (int ks = 0; ks < 4; ++ks) { lap[ks][0] = 0.f; lap[ks][1] = 0.f; }
#pragma unroll
  for (int j = 0; j < 7; ++j) {
    const int col = Lc[7 * n + j];           // scalar load
    const float v = Lv[7 * n + j];
    uintx4 g = *(const uintx4*)(xT + (size_t)col * 256 + voff);
#pragma unroll
    for (int ks = 0; ks < 4; ++ks) {
      float2 p = unpackbf2(g[ks]);
      lap[ks][0] = fmaf(v, p.x, lap[ks][0]);
      lap[ks][1] = fmaf(v, p.y, lap[ks][1]);
    }
  }

  // composite grad-ew / grad-ns: 54 gathers from L3-resident xT
  float ea[4][2], na[4][2];
#pragma unroll
  for (int ks = 0; ks < 4; ++ks) {
    ea[ks][0] = 0.f; ea[ks][1] = 0.f;
    na[ks][0] = 0.f; na[ks][1] = 0.f;
  }
  const int*   cb = cols + (size_t)n * 64;
  const float* eb = wew  + (size_t)n * 64;
  const float* nb = wns  + (size_t)n * 64;
#pragma unroll 6
  for (int j = 0; j < 54; ++j) {
    const int   c  = cb[j];                  // scalar loads (wave-uniform)
    const float ve = eb[j];
    const float vn = nb[j];
    uintx4 g = *(const uintx4*)(xT + (size_t)c * 256 + voff);
#pragma unroll
    for (int ks = 0; ks < 4; ++ks) {
      float2 p = unpackbf2(g[ks]);
      ea[ks][0] = fmaf(ve, p.x, ea[ks][0]); ea[ks][1] = fmaf(ve, p.y, ea[ks][1]);
      na[ks][0] = fmaf(vn, p.x, na[ks][0]); na[ks][1] = fmaf(vn, p.y, na[ks][1]);
    }
  }

  // A-fragments
  shortx8 afr[4];
#pragma unroll
  for (int ks = 0; ks < 4; ++ks) {
    float2 ip = unpackbf2(idw[ks]);
    shortx8 a;
    a[0] = bfr(ip.x);      a[1] = bfr(lap[ks][0]);
    a[2] = bfr(ea[ks][0]); a[3] = bfr(na[ks][0]);
    a[4] = bfr(ip.y);      a[5] = bfr(lap[ks][1]);
    a[6] = bfr(ea[ks][1]); a[7] = bfr(na[ks][1]);
    afr[ks] = a;
  }

  // MFMA with preconverted B-fragments
  float b0 = bias[bm], b1 = bias[16 + bm];
  floatx4 acc0 = {b0, b0, b0, b0};
  floatx4 acc1 = {b1, b1, b1, b1};
#pragma unroll
  for (int ks = 0; ks < 4; ++ks) {
    shortx8 bf0 = *(const shortx8*)(wsW + ((size_t)(ks * 2 + 0) * 64 + lane) * 8);
    acc0 = __builtin_amdgcn_mfma_f32_16x16x32_bf16(afr[ks], bf0, acc0, 0, 0, 0);
    shortx8 bf1 = *(const shortx8*)(wsW + ((size_t)(ks * 2 + 1) * 64 + lane) * 8);
    acc1 = __builtin_amdgcn_mfma_f32_16x16x32_bf16(afr[ks], bf1, acc1, 0, 0, 0);
  }

  // C/D layout: col = lane&15, row = (lane>>4)*4+reg; plain stores (L2 merges)
#pragma unroll
  for (int reg = 0; reg < 4; ++reg) {
    int b = h * 4 + reg;
    out[(size_t)(b * 32 + bm) * NVERT + n]      = acc0[reg];
    out[(size_t)(b * 32 + 16 + bm) * NVERT + n] = acc1[reg];
  }
}

extern "C" void kernel_launch(void* const* d_in, const int* in_sizes, int n_in,
                              void* d_out, int out_size, void* d_ws, size_t ws_size,
                              hipStream_t stream) {
  const float* x      = (const float*)d_in[0];
  const int*   Gc     = (const int*)  d_in[2];
  const float* Gv     = (const float*)d_in[3];
  const int*   Lc     = (const int*)  d_in[5];
  const float* Lv     = (const float*)d_in[6];
  const int*   Fc     = (const int*)  d_in[8];
  const float* Fv     = (const float*)d_in[9];
  const float* EW     = (const float*)d_in[10];
  const float* NS     = (const float*)d_in[11];
  const float* coeffs = (const float*)d_in[12];
  const float* bias   = (const float*)d_in[13];
  float* out = (float*)d_out;

  uint*  xT   = (uint*)d_ws;                         // NVERT*256 u32 (~40 MB)
  int*   cols = (int*)(xT + (size_t)NVERT * 256);    // NVERT*64 int
  float* wewT = (float*)(cols + (size_t)NVERT * 64); // NVERT*64 f32
  float* wnsT = wewT + (size_t)NVERT * 64;           // NVERT*64 f32
  short* wsW  = (short*)(wnsT + (size_t)NVERT * 64); // 4 KB of B-fragments

  dim3 gT((NVERT + 31) / 32, 16);
  k_transpose<<<gT, 256, 0, stream>>>(x, xT);
  k_prepw<<<1, 256, 0, stream>>>(coeffs, wsW);
  k_prep<<<(NVERT * 6 + 255) / 256, 256, 0, stream>>>(Fc, Fv, Gc, Gv, EW, NS,
                                                      cols, wewT, wnsT);
  k_vfused<<<GRID_V, 256, 0, stream>>>(xT, Lc, Lv, cols, wewT, wnsT,
                                       wsW, bias, out);
}

// Round 9
// 457.021 us; speedup vs baseline: 1.2907x; 1.2907x over previous
//
#include <hip/hip_runtime.h>
#include <hip/hip_bf16.h>

#define NVERT 40962
#define NFACE 81920
#define NPAIR_V 20481            // vertex pairs (2*20481 = 40962 exactly)
#define GRID_VP 5121             // ceil(20481/4)
#define GRID_FP 10240            // (81920/2)/4

typedef unsigned int uint;
typedef __attribute__((ext_vector_type(4))) uint  uintx4;
typedef __attribute__((ext_vector_type(4))) float floatx4;
typedef __attribute__((ext_vector_type(8))) short shortx8;

// ---------- bf16 helpers (RNE) ----------
__device__ __forceinline__ uint packbf2(float a, float b) {
  uint ua = __float_as_uint(a); ua = ua + 0x7fffu + ((ua >> 16) & 1u);
  uint ub = __float_as_uint(b); ub = ub + 0x7fffu + ((ub >> 16) & 1u);
  return (ua >> 16) | (ub & 0xffff0000u);
}
__device__ __forceinline__ float2 unpackbf2(uint u) {
  float2 r;
  r.x = __uint_as_float(u << 16);
  r.y = __uint_as_float(u & 0xffff0000u);
  return r;
}
__device__ __forceinline__ short bfr(float x) {
  uint u = __float_as_uint(x);
  u = u + 0x7fffu + ((u >> 16) & 1u);
  return (short)(u >> 16);
}

// bijective XCD swizzle (m204)
__device__ __forceinline__ int swz(int blk, int nwg) {
  int q = nwg >> 3, r = nwg & 7;
  int xcd = blk & 7, idx = blk >> 3;
  return (xcd < r ? xcd * (q + 1) : r * (q + 1) + (xcd - r) * q) + idx;
}

// Chunk-row layout (128 u32 words = 256 bc of one 8-batch chunk):
//   word q = (h*8 + b_l)*4 + ks  <->  channels (b_l, c = 8*ks + 2*h + {0,1})
// Lane l (h=l>>4, b_l=l&7, vx=(l>>3)&1) reads dwordx4 at word offset
//   Wl = (h*8 + b_l)*4  -> words ks=0..3 = exactly its A-frag k-slices.

// ---------- K0: transpose x[512,NV] f32 -> xT[2][NV][128] bf16x2 ------------
__global__ __launch_bounds__(256) void k_transpose(const float* __restrict__ x,
                                                   uint* __restrict__ xT) {
  __shared__ float tile[32][33];
  int n0 = blockIdx.x * 32;
  int r0 = blockIdx.y * 32;
  int tx = threadIdx.x & 31;
  int ty = threadIdx.x >> 5;
#pragma unroll
  for (int i = 0; i < 32; i += 8) {
    int n = n0 + tx;
    tile[ty + i][tx] = (n < NVERT)
        ? __builtin_nontemporal_load(&x[(size_t)(r0 + ty + i) * NVERT + n]) : 0.f;
  }
  __syncthreads();
#pragma unroll
  for (int i = 0; i < 32; i += 16) {
    int nl = (threadIdx.x >> 4) + i;
    int u  = threadIdx.x & 15;
    int n  = n0 + nl;
    int ug = 16 * blockIdx.y + u;            // global bc-pair index [0,256)
    int chunk = ug >> 7;                     // b>>3
    int q = ((ug & 3) * 8 + ((ug >> 4) & 7)) * 4 + ((ug >> 2) & 3);
    if (n < NVERT)
      xT[(size_t)chunk * NVERT * 128 + (size_t)n * 128 + q] =
          packbf2(tile[2 * u][nl], tile[2 * u + 1][nl]);
  }
}

// ---------- K0b: pre-convert coeffs -> bf16 MFMA B-fragments ----------
__global__ __launch_bounds__(256) void k_prepw(const float* __restrict__ coeffs,
                                               short* __restrict__ wsW) {
  int t = threadIdx.x;
  int ks = t >> 6, lane = t & 63;
  int bm = lane & 15, h = lane >> 4;
  const float* wp0 = coeffs + (size_t)bm * 128 + 32 * ks + 8 * h;
  shortx8 f0, f1;
#pragma unroll
  for (int j = 0; j < 8; ++j) {
    f0[j] = bfr(wp0[j]);
    f1[j] = bfr(wp0[16 * 128 + j]);
  }
  *(shortx8*)(wsW + ((size_t)(ks * 2 + 0) * 64 + lane) * 8) = f0;
  *(shortx8*)(wsW + ((size_t)(ks * 2 + 1) * 64 + lane) * 8) = f1;
}

// ---------- K1: two faces per wave (half-wave interleave) -> gf[NF][256] ----
__global__ __launch_bounds__(256) void k_faces(
    const uint* __restrict__ xTc,
    const int* __restrict__ Gc, const float* __restrict__ Gv,
    const float* __restrict__ EW, const float* __restrict__ NS,
    uint* __restrict__ gf) {
  const int t = threadIdx.x, lane = t & 63;
  const int p = __builtin_amdgcn_readfirstlane(swz(blockIdx.x, GRID_FP) * 4 + (t >> 6));
  const int fA = 2 * p, fB = 2 * p + 1;
  const int vx = (lane >> 3) & 1;
  const int Wl = ((lane >> 4) * 8 + (lane & 7)) * 4;

  // wave-uniform scalar tables for both faces
  int   colA[9], colB[9];
  float veA[9], vnA[9], veB[9], vnB[9];
#pragma unroll
  for (int comp = 0; comp < 3; ++comp) {
    const float eA = EW[3 * fA + comp], sA = NS[3 * fA + comp];
    const float eB = EW[3 * fB + comp], sB = NS[3 * fB + comp];
    const int baA = comp * (3 * NFACE) + 3 * fA;
    const int baB = comp * (3 * NFACE) + 3 * fB;
#pragma unroll
    for (int k = 0; k < 3; ++k) {
      const int i = comp * 3 + k;
      colA[i] = Gc[baA + k];  colB[i] = Gc[baB + k];
      const float gA = Gv[baA + k], gB = Gv[baB + k];
      veA[i] = gA * eA; vnA[i] = gA * sA;
      veB[i] = gB * eB; vnB[i] = gB * sB;
    }
  }

  float ea[4][2], sa[4][2];
#pragma unroll
  for (int ks = 0; ks < 4; ++ks) {
    ea[ks][0] = 0.f; ea[ks][1] = 0.f;
    sa[ks][0] = 0.f; sa[ks][1] = 0.f;
  }
#pragma unroll
  for (int i = 0; i < 9; ++i) {
    const int   col = vx ? colB[i] : colA[i];
    const float ve  = vx ? veB[i]  : veA[i];
    const float vn  = vx ? vnB[i]  : vnA[i];
    uintx4 g = *(const uintx4*)(xTc + (size_t)col * 128 + Wl);
#pragma unroll
    for (int ks = 0; ks < 4; ++ks) {
      float2 pv = unpackbf2(g[ks]);
      ea[ks][0] = fmaf(ve, pv.x, ea[ks][0]); ea[ks][1] = fmaf(ve, pv.y, ea[ks][1]);
      sa[ks][0] = fmaf(vn, pv.x, sa[ks][0]); sa[ks][1] = fmaf(vn, pv.y, sa[ks][1]);
    }
  }
  uintx4 we, wn;
#pragma unroll
  for (int ks = 0; ks < 4; ++ks) {
    we[ks] = packbf2(ea[ks][0], ea[ks][1]);
    wn[ks] = packbf2(sa[ks][0], sa[ks][1]);
  }
  uint* op = gf + (size_t)(fA + vx) * 256 + Wl;
  *(uintx4*)op         = we;
  *(uintx4*)(op + 128) = wn;
}

// ---------- K2: two vertices per wave, MFMA channel mix ---------------------
__global__ __launch_bounds__(256) void k_verts(
    const uint* __restrict__ xTc,
    const int* __restrict__ Lc, const float* __restrict__ Lv,
    const int* __restrict__ Fc, const float* __restrict__ Fv,
    const uint* __restrict__ gf,
    const short* __restrict__ wsW, const float* __restrict__ bias,
    float* __restrict__ out, int bbase) {
  const int t = threadIdx.x, lane = t & 63;
  const int p = __builtin_amdgcn_readfirstlane(swz(blockIdx.x, GRID_VP) * 4 + (t >> 6));
  if (p >= NPAIR_V) return;
  const int nA = 2 * p, nB = 2 * p + 1;
  const int vx = (lane >> 3) & 1;
  const int Wl = ((lane >> 4) * 8 + (lane & 7)) * 4;
  const int h = lane >> 4, bm = lane & 15;

  // wave-uniform scalar tables for both vertices
  int lcA[7], lcB[7]; float lvA[7], lvB[7];
#pragma unroll
  for (int j = 0; j < 7; ++j) {
    lcA[j] = Lc[7 * nA + j]; lvA[j] = Lv[7 * nA + j];
    lcB[j] = Lc[7 * nB + j]; lvB[j] = Lv[7 * nB + j];
  }
  int fcA[6], fcB[6]; float fvA[6], fvB[6];
#pragma unroll
  for (int j = 0; j < 6; ++j) {
    fcA[j] = Fc[6 * nA + j]; fvA[j] = Fv[6 * nA + j];
    fcB[j] = Fc[6 * nB + j]; fvB[j] = Fv[6 * nB + j];
  }

  // identity row (own vertex per half)
  uintx4 idw = *(const uintx4*)(xTc + (size_t)(nA + vx) * 128 + Wl);

  // Laplacian
  float lap[4][2];
#pragma unroll
  for (int ks = 0; ks < 4; ++ks) { lap[ks][0] = 0.f; lap[ks][1] = 0.f; }
#pragma unroll
  for (int j = 0; j < 7; ++j) {
    const int   col = vx ? lcB[j] : lcA[j];
    const float v   = vx ? lvB[j] : lvA[j];
    uintx4 g = *(const uintx4*)(xTc + (size_t)col * 128 + Wl);
#pragma unroll
    for (int ks = 0; ks < 4; ++ks) {
      float2 pv = unpackbf2(g[ks]);
      lap[ks][0] = fmaf(v, pv.x, lap[ks][0]);
      lap[ks][1] = fmaf(v, pv.y, lap[ks][1]);
    }
  }

  // F2V averaging of face gradients
  float ea[4][2], na[4][2];
#pragma unroll
  for (int ks = 0; ks < 4; ++ks) {
    ea[ks][0] = 0.f; ea[ks][1] = 0.f;
    na[ks][0] = 0.f; na[ks][1] = 0.f;
  }
#pragma unroll
  for (int j = 0; j < 6; ++j) {
    const int   fc = vx ? fcB[j] : fcA[j];
    const float v  = vx ? fvB[j] : fvA[j];
    const uint* rp = gf + (size_t)fc * 256 + Wl;
    uintx4 ge = *(const uintx4*)rp;
    uintx4 gn = *(const uintx4*)(rp + 128);
#pragma unroll
    for (int ks = 0; ks < 4; ++ks) {
      float2 a = unpackbf2(ge[ks]);
      float2 b = unpackbf2(gn[ks]);
      ea[ks][0] = fmaf(v, a.x, ea[ks][0]); ea[ks][1] = fmaf(v, a.y, ea[ks][1]);
      na[ks][0] = fmaf(v, b.x, na[ks][0]); na[ks][1] = fmaf(v, b.y, na[ks][1]);
    }
  }

  // A-fragments
  shortx8 afr[4];
#pragma unroll
  for (int ks = 0; ks < 4; ++ks) {
    float2 ip = unpackbf2(idw[ks]);
    shortx8 a;
    a[0] = bfr(ip.x);      a[1] = bfr(lap[ks][0]);
    a[2] = bfr(ea[ks][0]); a[3] = bfr(na[ks][0]);
    a[4] = bfr(ip.y);      a[5] = bfr(lap[ks][1]);
    a[6] = bfr(ea[ks][1]); a[7] = bfr(na[ks][1]);
    afr[ks] = a;
  }

  // MFMA
  float b0 = bias[bm], b1 = bias[16 + bm];
  floatx4 acc0 = {b0, b0, b0, b0};
  floatx4 acc1 = {b1, b1, b1, b1};
#pragma unroll
  for (int ks = 0; ks < 4; ++ks) {
    shortx8 bf0 = *(const shortx8*)(wsW + ((size_t)(ks * 2 + 0) * 64 + lane) * 8);
    acc0 = __builtin_amdgcn_mfma_f32_16x16x32_bf16(afr[ks], bf0, acc0, 0, 0, 0);
    shortx8 bf1 = *(const shortx8*)(wsW + ((size_t)(ks * 2 + 1) * 64 + lane) * 8);
    acc1 = __builtin_amdgcn_mfma_f32_16x16x32_bf16(afr[ks], bf1, acc1, 0, 0, 0);
  }

  // C/D: col = lane&15, row m = h*4+reg -> vertex = m>>3, b_l = m&7
  const int nst = (h >> 1) ? nB : nA;
  const int blb = 4 * (h & 1);
#pragma unroll
  for (int reg = 0; reg < 4; ++reg) {
    const int bg = bbase + blb + reg;
    out[(size_t)(bg * 32 + bm) * NVERT + nst]      = acc0[reg];
    out[(size_t)(bg * 32 + 16 + bm) * NVERT + nst] = acc1[reg];
  }
}

extern "C" void kernel_launch(void* const* d_in, const int* in_sizes, int n_in,
                              void* d_out, int out_size, void* d_ws, size_t ws_size,
                              hipStream_t stream) {
  const float* x      = (const float*)d_in[0];
  const int*   Gc     = (const int*)  d_in[2];
  const float* Gv     = (const float*)d_in[3];
  const int*   Lc     = (const int*)  d_in[5];
  const float* Lv     = (const float*)d_in[6];
  const int*   Fc     = (const int*)  d_in[8];
  const float* Fv     = (const float*)d_in[9];
  const float* EW     = (const float*)d_in[10];
  const float* NS     = (const float*)d_in[11];
  const float* coeffs = (const float*)d_in[12];
  const float* bias   = (const float*)d_in[13];
  float* out = (float*)d_out;

  uint*  xT  = (uint*)d_ws;                          // 2 * NVERT * 128 u32 (~40 MB)
  uint*  gf  = xT + (size_t)2 * NVERT * 128;         // NFACE * 256 u32 (82 MB, reused per chunk)
  short* wsW = (short*)(gf + (size_t)NFACE * 256);   // 4 KB B-fragments

  dim3 gT((NVERT + 31) / 32, 16);
  k_transpose<<<gT, 256, 0, stream>>>(x, xT);
  k_prepw<<<1, 256, 0, stream>>>(coeffs, wsW);
  for (int c = 0; c < 2; ++c) {
    const uint* xTc = xT + (size_t)c * NVERT * 128;
    k_faces<<<GRID_FP, 256, 0, stream>>>(xTc, Gc, Gv, EW, NS, gf);
    k_verts<<<GRID_VP, 256, 0, stream>>>(xTc, Lc, Lv, Fc, Fv, gf, wsW, bias,
                                         out, c * 8);
  }
}